// Round 10
// baseline (155.787 us; speedup 1.0000x reference)
//
#include <hip/hip_runtime.h>
#include <hip/hip_bf16.h>
#include <math.h>

#define S_LEN 2048
#define BSZ 2
#define DM 512
#define NH 8
#define HD 64
#define RTOT (S_LEN*BSZ)             // 4096 rows, row r = s*BSZ + b
#define T_KEEP 32
#define ROW0 ((S_LEN - T_KEEP)*BSZ)  // 4032
#define NXELEM (RTOT*DM)             // 2097152
#define NWROW  (NH*192)              // 1536
#define NWELEM (NWROW*DM)            // 786432

typedef __attribute__((ext_vector_type(8))) _Float16 half8;
typedef __attribute__((ext_vector_type(4))) float floatx4;

__device__ __forceinline__ void gld16(const void* g, void* l) {
    __builtin_amdgcn_global_load_lds((const __attribute__((address_space(1))) void*)g,
                                     (__attribute__((address_space(3))) void*)l, 16, 0, 0);
}

__device__ __forceinline__ short cvt1(float v) {
    _Float16 h = (_Float16)v;
    return __builtin_bit_cast(short, h);
}

// ---- Kernel 0: fp32 -> fp16 planes + bias concat + gbar zero + bg fill --------
__global__ __launch_bounds__(256) void convert(
    const float* __restrict__ x,
    const float* __restrict__ Wq, const float* __restrict__ Wk, const float* __restrict__ Wv,
    const float* __restrict__ bq, const float* __restrict__ bk, const float* __restrict__ bv,
    const float* __restrict__ bo,
    short* __restrict__ xf, short* __restrict__ wf, float* __restrict__ bcat,
    float* __restrict__ gbar, float* __restrict__ out)
{
    const int g = blockIdx.x*blockDim.x + threadIdx.x;
    const int stride = gridDim.x*blockDim.x;
    const int total4 = (NXELEM + NWELEM)/4;
    for (int i = g; i < total4; i += stride) {
        float4 v; size_t dst; short* d;
        if (i < NXELEM/4) {
            v = ((const float4*)x)[i];
            dst = (size_t)i*4; d = xf;
        } else {
            int j = i - NXELEM/4;
            int e = j*4;
            int R = e >> 9;
            int k = e & 511;
            int t = R >> 6;                 // = h*3 + m
            int hh = (t*683) >> 11;         // t/3 for t<24
            int m = t - 3*hh;
            int c = R & 63;
            const float* W = (m == 0 ? Wq : (m == 1 ? Wk : Wv));
            v = *(const float4*)&W[(size_t)(hh*HD + c)*DM + k];
            dst = (size_t)R*DM + k; d = wf;
        }
        short4 hv;
        hv.x = cvt1(v.x); hv.y = cvt1(v.y); hv.z = cvt1(v.z); hv.w = cvt1(v.w);
        *(short4*)&d[dst] = hv;
    }
    // background fill: rows < ROW0 of out are just bo
    {
        const float4* b4 = (const float4*)bo;
        float4* o4 = (float4*)out;
        const int fill4 = ROW0*DM/4;
        for (int i = g; i < fill4; i += stride) o4[i] = b4[i & 127];
    }
    if (g < NWROW) {
        int t = g >> 6;
        int hh = (t*683) >> 11;
        int m = t - 3*hh;
        int c = g & 63;
        bcat[g] = (m == 0 ? bq : (m == 1 ? bk : bv))[hh*HD + c];
    }
    if (g < 2048) gbar[g] = 0.f;
}

// ------------- Kernel 1: fp16 MFMA qkv GEMM, 16-row tiles, 6 blocks/CU ---------
// grid (256, 8): block = 16 rows x head h's 192 cols. BK=32, 16 K-iterations.
// Wave w computes all 16 rows x cols [w*48, w*48+48) (3 acc tiles).
// LDS: 13 chunks x 1KB (chunk 0 = A rows, chunks 1..12 = B tiles t=0..11);
// C-dump 16x192 fp32 = 12KB reuses the stage.
__global__ __launch_bounds__(256, 6) void qkv_gemm(
    const _Float16* __restrict__ xf, const _Float16* __restrict__ wf,
    const float* __restrict__ bcat, const float* __restrict__ beta,
    float* __restrict__ gbar, float* __restrict__ qsel)
{
    __shared__ __align__(16) char smem[13312];
    __shared__ float sb[256];

    const int tid  = threadIdx.x;
    const int w    = tid >> 6;
    const int lane = tid & 63;
    const int lrow = lane & 15;
    const int lk8  = lane >> 4;
    const int h    = blockIdx.y;
    const int r0   = blockIdx.x * 16;

    floatx4 acc[3];
    #pragma unroll
    for (int j = 0; j < 3; ++j) acc[j] = (floatx4)0.f;

    // my staging chunks: c in {w, w+4, w+8, w+12} intersect [0,13)
    const _Float16* csrc[4];
    int cdst[4];
    int nch = 0;
    for (int c = w; c < 13; c += 4) {
        csrc[nch] = (c == 0)
            ? xf + (size_t)(r0 + lrow)*DM + lk8*8
            : wf + (size_t)(h*192 + (c-1)*16 + lrow)*DM + lk8*8;
        cdst[nch] = c;
        ++nch;
    }

    for (int kc = 0; kc < 16; ++kc) {
        const int ko = kc*32;
        for (int i = 0; i < nch; ++i)
            gld16(csrc[i] + ko, smem + cdst[i]*1024);
        __syncthreads();
        half8 a = *(const half8*)(smem + lane*16);
        #pragma unroll
        for (int j = 0; j < 3; ++j) {
            half8 b = *(const half8*)(smem + (1 + 3*w + j)*1024 + lane*16);
            acc[j] = __builtin_amdgcn_mfma_f32_16x16x32_f16(a, b, acc[j], 0, 0, 0);
        }
        __syncthreads();
    }

    // C dump (16 x 192 fp32 = 12KB, reuses stage)
    float* Cl = (float*)smem;
    #pragma unroll
    for (int j = 0; j < 3; ++j) {
        int col = w*48 + j*16 + lrow;
        float bias = bcat[h*192 + col];
        #pragma unroll
        for (int reg = 0; reg < 4; ++reg) {
            int row = lk8*4 + reg;          // 0..15
            Cl[row*192 + col] = acc[j][reg] + bias;
        }
    }
    sb[tid] = 0.f;
    __syncthreads();

    const float inv_scale = 1.0f / (8.0f * expf(beta[h]));
    float kacc0 = 0.f, kacc1 = 0.f, vacc0 = 0.f, vacc1 = 0.f;
    for (int i2 = w; i2 < 16; i2 += 4) {
        float qv = Cl[i2*192 + lane];
        float kv = Cl[i2*192 + 64 + lane];
        float vv = Cl[i2*192 + 128 + lane];
        int r = r0 + i2;
        int s = r >> 1;
        int b = r & 1;
        if ((s & 63) == 63) {
            int wi = s >> 6;
            qsel[((size_t)(b*NH + h)*T_KEEP + wi)*64 + lane] = qv;
        }
        float p = qv * kv;
        #pragma unroll
        for (int off = 32; off > 0; off >>= 1) p += __shfl_xor(p, off, 64);
        float sig = 1.0f / (1.0f + expf(-p * inv_scale));
        if (b == 0) { kacc0 += sig*kv; vacc0 += sig*vv; }
        else        { kacc1 += sig*kv; vacc1 += sig*vv; }
    }
    __syncthreads();

    atomicAdd(&sb[  0 + lane], kacc0);
    atomicAdd(&sb[ 64 + lane], vacc0);
    atomicAdd(&sb[128 + lane], kacc1);
    atomicAdd(&sb[192 + lane], vacc1);
    __syncthreads();
    {
        int b   = tid >> 7;
        int sel = (tid >> 6) & 1;
        int j   = tid & 63;
        int z   = b*NH + h;
        atomicAdd(&gbar[sel*1024 + z*64 + j], sb[tid]);
    }
}

// ------------- Kernel 2: per-z coef (softmax) + G row ------------------------
// grid 16 (z = b*8+h), block 256.
__global__ __launch_bounds__(256) void headk(
    const float* __restrict__ qsel, const float* __restrict__ beta,
    const float* __restrict__ gbar, const float* __restrict__ Wo,
    float* __restrict__ coef, float* __restrict__ G)
{
    const int z = blockIdx.x;
    const int h = z & 7;
    const int tid = threadIdx.x;

    __shared__ float s_kb[64], s_vb[64];
    __shared__ float s_part[T_KEEP][8];
    __shared__ float s_gp[64][4];

    if (tid < 64) {
        s_kb[tid] = gbar[z*64 + tid];
        s_vb[tid] = gbar[1024 + z*64 + tid];
    }
    __syncthreads();

    {
        int wi = tid >> 3, jg = tid & 7;
        const float* qrow = &qsel[((size_t)z*T_KEEP + wi)*64 + jg*8];
        float4 q1 = *(const float4*)qrow;
        float4 q2 = *(const float4*)(qrow + 4);
        int j0 = jg*8;
        float p = q1.x*s_kb[j0] + q1.y*s_kb[j0+1] + q1.z*s_kb[j0+2] + q1.w*s_kb[j0+3]
                + q2.x*s_kb[j0+4] + q2.y*s_kb[j0+5] + q2.z*s_kb[j0+6] + q2.w*s_kb[j0+7];
        s_part[wi][jg] = p;
    }
    __syncthreads();
    if (tid < T_KEEP) {
        float sc = 0.f;
        #pragma unroll
        for (int gg = 0; gg < 8; ++gg) sc += s_part[tid][gg];
        sc *= 1.0f / (8.0f * expf(beta[h]));
        float m = sc;
        #pragma unroll
        for (int off = 16; off > 0; off >>= 1) m = fmaxf(m, __shfl_xor(m, off, 64));
        m = fmaxf(m, 0.f);                       // sink logit = 0
        float e = expf(sc - m);
        float d = e;
        #pragma unroll
        for (int off = 16; off > 0; off >>= 1) d += __shfl_xor(d, off, 64);
        d += expf(-m);                           // sink term
        float c = e / d;
        if (tid == T_KEEP-1) c += 1.0f;          // iter-0 contribution
        coef[z*T_KEEP + tid] = c;
    }

    // G: 8 passes; 4 threads per column, 16 j each; LDS reduce
    const int cq = tid >> 2;
    const int jg = tid & 3;
    #pragma unroll
    for (int it = 0; it < 8; ++it) {
        int c = it*64 + cq;
        const float* wrow = &Wo[(size_t)c*DM + h*64 + jg*16];
        float a = 0.f;
        #pragma unroll
        for (int jj = 0; jj < 16; jj += 4) {
            float4 wv = *(const float4*)&wrow[jj];
            int j0 = jg*16 + jj;
            a += wv.x*s_vb[j0] + wv.y*s_vb[j0+1] + wv.z*s_vb[j0+2] + wv.w*s_vb[j0+3];
        }
        s_gp[cq][jg] = a;
        __syncthreads();
        if (tid < 64)
            G[(size_t)z*DM + it*64 + tid] = s_gp[tid][0] + s_gp[tid][1] + s_gp[tid][2] + s_gp[tid][3];
        __syncthreads();
    }
}

// ------------- Kernel 3: output rows from coef x G ---------------------------
__global__ __launch_bounds__(256) void outk3(
    const float* __restrict__ coef, const float* __restrict__ G,
    const float* __restrict__ bo, float* __restrict__ out)
{
    const int a = blockIdx.x;
    const int b = a & 1;
    const int wi = a >> 1;
    const int tid = threadIdx.x;
    __shared__ float s_cf[NH];
    if (tid < NH) s_cf[tid] = coef[(b*NH + tid)*T_KEEP + wi];
    __syncthreads();
    for (int c = tid; c < DM; c += 256) {
        float v = bo[c];
        #pragma unroll
        for (int h = 0; h < NH; ++h)
            v += s_cf[h] * G[(size_t)(b*NH + h)*DM + c];
        out[(size_t)(ROW0 + a)*DM + c] = v;
    }
}

extern "C" void kernel_launch(void* const* d_in, const int* in_sizes, int n_in,
                              void* d_out, int out_size, void* d_ws, size_t ws_size,
                              hipStream_t stream) {
    const float* x    = (const float*)d_in[0];
    const float* Wq   = (const float*)d_in[1];
    const float* bq   = (const float*)d_in[2];
    const float* Wk   = (const float*)d_in[3];
    const float* bk   = (const float*)d_in[4];
    const float* Wv   = (const float*)d_in[5];
    const float* bv   = (const float*)d_in[6];
    const float* Wo   = (const float*)d_in[7];
    const float* bo   = (const float*)d_in[8];
    const float* beta = (const float*)d_in[9];

    char* ws = (char*)d_ws;
    float* gbar = (float*)(ws + 0);           //   8 KB
    float* qsel = (float*)(ws + 8192);        // 128 KB
    float* bcat = (float*)(ws + 139264);      //   8 KB
    float* coef = (float*)(ws + 147456);      //   2 KB
    float* G    = (float*)(ws + 149504);      //  32 KB
    short* xf   = (short*)(ws + 182272);      //   4 MB
    short* wf   = (short*)(ws + 182272 + 4194304);   // 1.5 MB
    float* out  = (float*)d_out;

    convert<<<2048, 256, 0, stream>>>(x, Wq, Wk, Wv, bq, bk, bv, bo,
                                      xf, wf, bcat, gbar, out);
    dim3 g1(RTOT/16, NH);
    qkv_gemm<<<g1, 256, 0, stream>>>((const _Float16*)xf, (const _Float16*)wf,
                                     bcat, beta, gbar, qsel);
    headk<<<16, 256, 0, stream>>>(qsel, beta, gbar, Wo, coef, G);
    outk3<<<64, 256, 0, stream>>>(coef, G, bo, out);
}

// Round 11
// 130.570 us; speedup vs baseline: 1.1931x; 1.1931x over previous
//
#include <hip/hip_runtime.h>
#include <hip/hip_bf16.h>
#include <math.h>

#define S_LEN 2048
#define BSZ 2
#define DM 512
#define NH 8
#define HD 64
#define RTOT (S_LEN*BSZ)             // 4096 rows, row r = s*BSZ + b
#define T_KEEP 32
#define ROW0 ((S_LEN - T_KEEP)*BSZ)  // 4032
#define NXELEM (RTOT*DM)             // 2097152
#define NWROW  (NH*192)              // 1536
#define NWELEM (NWROW*DM)            // 786432

typedef __attribute__((ext_vector_type(8))) _Float16 half8;
typedef __attribute__((ext_vector_type(4))) float floatx4;

__device__ __forceinline__ short cvt1(float v) {
    _Float16 h = (_Float16)v;
    return __builtin_bit_cast(short, h);
}

// ---- Kernel 0: fp32 -> fp16 planes + bias concat + gbar zero + bg fill --------
__global__ __launch_bounds__(256) void convert(
    const float* __restrict__ x,
    const float* __restrict__ Wq, const float* __restrict__ Wk, const float* __restrict__ Wv,
    const float* __restrict__ bq, const float* __restrict__ bk, const float* __restrict__ bv,
    const float* __restrict__ bo,
    short* __restrict__ xf, short* __restrict__ wf, float* __restrict__ bcat,
    float* __restrict__ gbar, float* __restrict__ out)
{
    const int g = blockIdx.x*blockDim.x + threadIdx.x;
    const int stride = gridDim.x*blockDim.x;
    const int total4 = (NXELEM + NWELEM)/4;
    for (int i = g; i < total4; i += stride) {
        float4 v; size_t dst; short* d;
        if (i < NXELEM/4) {
            v = ((const float4*)x)[i];
            dst = (size_t)i*4; d = xf;
        } else {
            int j = i - NXELEM/4;
            int e = j*4;
            int R = e >> 9;
            int k = e & 511;
            int t = R >> 6;                 // = h*3 + m
            int hh = (t*683) >> 11;         // t/3 for t<24
            int m = t - 3*hh;
            int c = R & 63;
            const float* W = (m == 0 ? Wq : (m == 1 ? Wk : Wv));
            v = *(const float4*)&W[(size_t)(hh*HD + c)*DM + k];
            dst = (size_t)R*DM + k; d = wf;
        }
        short4 hv;
        hv.x = cvt1(v.x); hv.y = cvt1(v.y); hv.z = cvt1(v.z); hv.w = cvt1(v.w);
        *(short4*)&d[dst] = hv;
    }
    // background fill: rows < ROW0 of out are just bo
    {
        const float4* b4 = (const float4*)bo;
        float4* o4 = (float4*)out;
        const int fill4 = ROW0*DM/4;
        for (int i = g; i < fill4; i += stride) o4[i] = b4[i & 127];
    }
    if (g < NWROW) {
        int t = g >> 6;
        int hh = (t*683) >> 11;
        int m = t - 3*hh;
        int c = g & 63;
        bcat[g] = (m == 0 ? bq : (m == 1 ? bk : bv))[hh*HD + c];
    }
    if (g < 2048) gbar[g] = 0.f;
}

// ------------- Kernel 1: fp16 MFMA qkv GEMM, register-pipelined K loop ---------
// grid (64, 8): block = 64 rows x head h's 192 cols. Waves 2x2 (32r x 96c each).
// Fragments loaded directly from global (fragment layout == memory layout:
// lane l -> row l&15, k (l>>4)*8, 16B). Register double-buffer, full unroll.
// __launch_bounds__(256, 2): min 2 waves/EU -> 256-VGPR cap so BOTH fragment
// buffers stay live (r8's bare bounds gave VGPR=80 and serialized the loads).
__global__ __launch_bounds__(256, 2) void qkv_gemm(
    const _Float16* __restrict__ xf, const _Float16* __restrict__ wf,
    const float* __restrict__ bcat, const float* __restrict__ beta,
    float* __restrict__ gbar, float* __restrict__ qsel)
{
    __shared__ __align__(16) float Cl[32*192];   // 24KB C-dump (two halves)
    __shared__ float sb[256];

    const int tid  = threadIdx.x;
    const int w    = tid >> 6;
    const int lane = tid & 63;
    const int lrow = lane & 15;
    const int lk8  = lane >> 4;
    const int h    = blockIdx.y;
    const int r0   = blockIdx.x * 64;
    const int rowg = w >> 1;
    const int colg = w & 1;

    floatx4 acc[2][6];
    #pragma unroll
    for (int i = 0; i < 2; ++i)
        #pragma unroll
        for (int j = 0; j < 6; ++j) acc[i][j] = (floatx4)0.f;

    const _Float16* pA = xf + (size_t)(r0 + rowg*32 + lrow)*DM + lk8*8;
    const _Float16* pB = wf + (size_t)(h*192 + colg*96 + lrow)*DM + lk8*8;

    half8 Ab[2][2], Bb[2][6];
    #pragma unroll
    for (int i = 0; i < 2; ++i) Ab[0][i] = *(const half8*)(pA + (size_t)i*16*DM);
    #pragma unroll
    for (int j = 0; j < 6; ++j) Bb[0][j] = *(const half8*)(pB + (size_t)j*16*DM);

    #pragma unroll
    for (int kc = 0; kc < 16; ++kc) {
        const int buf = kc & 1;
        if (kc < 15) {
            const int nb = buf ^ 1;
            const int ko = (kc + 1)*32;
            #pragma unroll
            for (int i = 0; i < 2; ++i)
                Ab[nb][i] = *(const half8*)(pA + (size_t)i*16*DM + ko);
            #pragma unroll
            for (int j = 0; j < 6; ++j)
                Bb[nb][j] = *(const half8*)(pB + (size_t)j*16*DM + ko);
        }
        #pragma unroll
        for (int j = 0; j < 6; ++j)
            #pragma unroll
            for (int i = 0; i < 2; ++i)
                acc[i][j] = __builtin_amdgcn_mfma_f32_16x16x32_f16(Ab[buf][i], Bb[buf][j], acc[i][j], 0, 0, 0);
    }

    // epilogue in two 32-row halves (Cl = 32x192 fp32 = 24KB)
    sb[tid] = 0.f;
    const float inv_scale = 1.0f / (8.0f * expf(beta[h]));
    float kacc0 = 0.f, kacc1 = 0.f, vacc0 = 0.f, vacc1 = 0.f;

    #pragma unroll
    for (int half = 0; half < 2; ++half) {
        __syncthreads();
        if (rowg == half) {
            #pragma unroll
            for (int i = 0; i < 2; ++i) {
                #pragma unroll
                for (int j = 0; j < 6; ++j) {
                    int col = colg*96 + j*16 + lrow;
                    float bias = bcat[h*192 + col];
                    #pragma unroll
                    for (int reg = 0; reg < 4; ++reg) {
                        int row = i*16 + lk8*4 + reg;   // 0..31 within half
                        Cl[row*192 + col] = acc[i][j][reg] + bias;
                    }
                }
            }
        }
        __syncthreads();
        for (int i2 = w; i2 < 32; i2 += 4) {
            float qv = Cl[i2*192 + lane];
            float kv = Cl[i2*192 + 64 + lane];
            float vv = Cl[i2*192 + 128 + lane];
            int r = r0 + half*32 + i2;
            int s = r >> 1;
            int b = r & 1;
            if ((s & 63) == 63) {
                int wi = s >> 6;
                qsel[((size_t)(b*NH + h)*T_KEEP + wi)*64 + lane] = qv;
            }
            float p = qv * kv;
            #pragma unroll
            for (int off = 32; off > 0; off >>= 1) p += __shfl_xor(p, off, 64);
            float sig = 1.0f / (1.0f + expf(-p * inv_scale));
            if (b == 0) { kacc0 += sig*kv; vacc0 += sig*vv; }
            else        { kacc1 += sig*kv; vacc1 += sig*vv; }
        }
    }
    __syncthreads();

    atomicAdd(&sb[  0 + lane], kacc0);
    atomicAdd(&sb[ 64 + lane], vacc0);
    atomicAdd(&sb[128 + lane], kacc1);
    atomicAdd(&sb[192 + lane], vacc1);
    __syncthreads();
    {
        int b   = tid >> 7;
        int sel = (tid >> 6) & 1;
        int j   = tid & 63;
        int z   = b*NH + h;
        atomicAdd(&gbar[sel*1024 + z*64 + j], sb[tid]);
    }
}

// ------------- Kernel 2: per-z coef (softmax) + G row ------------------------
// grid 16 (z = b*8+h), block 256.
__global__ __launch_bounds__(256) void headk(
    const float* __restrict__ qsel, const float* __restrict__ beta,
    const float* __restrict__ gbar, const float* __restrict__ Wo,
    float* __restrict__ coef, float* __restrict__ G)
{
    const int z = blockIdx.x;
    const int h = z & 7;
    const int tid = threadIdx.x;

    __shared__ float s_kb[64], s_vb[64];
    __shared__ float s_part[T_KEEP][8];
    __shared__ float s_gp[64][4];

    if (tid < 64) {
        s_kb[tid] = gbar[z*64 + tid];
        s_vb[tid] = gbar[1024 + z*64 + tid];
    }
    __syncthreads();

    {
        int wi = tid >> 3, jg = tid & 7;
        const float* qrow = &qsel[((size_t)z*T_KEEP + wi)*64 + jg*8];
        float4 q1 = *(const float4*)qrow;
        float4 q2 = *(const float4*)(qrow + 4);
        int j0 = jg*8;
        float p = q1.x*s_kb[j0] + q1.y*s_kb[j0+1] + q1.z*s_kb[j0+2] + q1.w*s_kb[j0+3]
                + q2.x*s_kb[j0+4] + q2.y*s_kb[j0+5] + q2.z*s_kb[j0+6] + q2.w*s_kb[j0+7];
        s_part[wi][jg] = p;
    }
    __syncthreads();
    if (tid < T_KEEP) {
        float sc = 0.f;
        #pragma unroll
        for (int gg = 0; gg < 8; ++gg) sc += s_part[tid][gg];
        sc *= 1.0f / (8.0f * expf(beta[h]));
        float m = sc;
        #pragma unroll
        for (int off = 16; off > 0; off >>= 1) m = fmaxf(m, __shfl_xor(m, off, 64));
        m = fmaxf(m, 0.f);                       // sink logit = 0
        float e = expf(sc - m);
        float d = e;
        #pragma unroll
        for (int off = 16; off > 0; off >>= 1) d += __shfl_xor(d, off, 64);
        d += expf(-m);                           // sink term
        float c = e / d;
        if (tid == T_KEEP-1) c += 1.0f;          // iter-0 contribution
        coef[z*T_KEEP + tid] = c;
    }

    // G: 8 passes; 4 threads per column, 16 j each; LDS reduce
    const int cq = tid >> 2;
    const int jg = tid & 3;
    #pragma unroll
    for (int it = 0; it < 8; ++it) {
        int c = it*64 + cq;
        const float* wrow = &Wo[(size_t)c*DM + h*64 + jg*16];
        float a = 0.f;
        #pragma unroll
        for (int jj = 0; jj < 16; jj += 4) {
            float4 wv = *(const float4*)&wrow[jj];
            int j0 = jg*16 + jj;
            a += wv.x*s_vb[j0] + wv.y*s_vb[j0+1] + wv.z*s_vb[j0+2] + wv.w*s_vb[j0+3];
        }
        s_gp[cq][jg] = a;
        __syncthreads();
        if (tid < 64)
            G[(size_t)z*DM + it*64 + tid] = s_gp[tid][0] + s_gp[tid][1] + s_gp[tid][2] + s_gp[tid][3];
        __syncthreads();
    }
}

// ------------- Kernel 3: output rows from coef x G ---------------------------
__global__ __launch_bounds__(256) void outk3(
    const float* __restrict__ coef, const float* __restrict__ G,
    const float* __restrict__ bo, float* __restrict__ out)
{
    const int a = blockIdx.x;
    const int b = a & 1;
    const int wi = a >> 1;
    const int tid = threadIdx.x;
    __shared__ float s_cf[NH];
    if (tid < NH) s_cf[tid] = coef[(b*NH + tid)*T_KEEP + wi];
    __syncthreads();
    for (int c = tid; c < DM; c += 256) {
        float v = bo[c];
        #pragma unroll
        for (int h = 0; h < NH; ++h)
            v += s_cf[h] * G[(size_t)(b*NH + h)*DM + c];
        out[(size_t)(ROW0 + a)*DM + c] = v;
    }
}

extern "C" void kernel_launch(void* const* d_in, const int* in_sizes, int n_in,
                              void* d_out, int out_size, void* d_ws, size_t ws_size,
                              hipStream_t stream) {
    const float* x    = (const float*)d_in[0];
    const float* Wq   = (const float*)d_in[1];
    const float* bq   = (const float*)d_in[2];
    const float* Wk   = (const float*)d_in[3];
    const float* bk   = (const float*)d_in[4];
    const float* Wv   = (const float*)d_in[5];
    const float* bv   = (const float*)d_in[6];
    const float* Wo   = (const float*)d_in[7];
    const float* bo   = (const float*)d_in[8];
    const float* beta = (const float*)d_in[9];

    char* ws = (char*)d_ws;
    float* gbar = (float*)(ws + 0);           //   8 KB
    float* qsel = (float*)(ws + 8192);        // 128 KB
    float* bcat = (float*)(ws + 139264);      //   8 KB
    float* coef = (float*)(ws + 147456);      //   2 KB
    float* G    = (float*)(ws + 149504);      //  32 KB
    short* xf   = (short*)(ws + 182272);      //   4 MB
    short* wf   = (short*)(ws + 182272 + 4194304);   // 1.5 MB
    float* out  = (float*)d_out;

    convert<<<2048, 256, 0, stream>>>(x, Wq, Wk, Wv, bq, bk, bv, bo,
                                      xf, wf, bcat, gbar, out);
    dim3 g1(RTOT/64, NH);
    qkv_gemm<<<g1, 256, 0, stream>>>((const _Float16*)xf, (const _Float16*)wf,
                                     bcat, beta, gbar, qsel);
    headk<<<16, 256, 0, stream>>>(qsel, beta, gbar, Wo, coef, G);
    outk3<<<64, 256, 0, stream>>>(coef, G, bo, out);
}

// Round 12
// 125.629 us; speedup vs baseline: 1.2401x; 1.0393x over previous
//
#include <hip/hip_runtime.h>
#include <hip/hip_bf16.h>
#include <math.h>

#define S_LEN 2048
#define BSZ 2
#define DM 512
#define NH 8
#define HD 64
#define RTOT (S_LEN*BSZ)             // 4096 rows, row r = s*BSZ + b
#define T_KEEP 32
#define ROW0 ((S_LEN - T_KEEP)*BSZ)  // 4032
#define NXELEM (RTOT*DM)             // 2097152
#define NWROW  (NH*128)              // 1024 (per-head q|k rows)
#define NWELEM (NWROW*DM)            // 524288

typedef __attribute__((ext_vector_type(8))) _Float16 half8;
typedef __attribute__((ext_vector_type(4))) float floatx4;

__device__ __forceinline__ void gld16(const void* g, void* l) {
    __builtin_amdgcn_global_load_lds((const __attribute__((address_space(1))) void*)g,
                                     (__attribute__((address_space(3))) void*)l, 16, 0, 0);
}

__device__ __forceinline__ short cvt1(float v) {
    _Float16 h = (_Float16)v;
    return __builtin_bit_cast(short, h);
}

// ---- Kernel 0: fp32 -> fp16 planes (x, Wq|Wk) + bcat + zero sig/sbar/Ssum + bg fill
__global__ __launch_bounds__(256) void convert(
    const float* __restrict__ x,
    const float* __restrict__ Wq, const float* __restrict__ Wk,
    const float* __restrict__ bq, const float* __restrict__ bk,
    const float* __restrict__ bo,
    short* __restrict__ xf, short* __restrict__ wf, float* __restrict__ bcat,
    float* __restrict__ sig, float* __restrict__ sbar, float* __restrict__ Ssum,
    float* __restrict__ out)
{
    const int g = blockIdx.x*blockDim.x + threadIdx.x;
    const int stride = gridDim.x*blockDim.x;
    const int total4 = (NXELEM + NWELEM)/4;
    for (int i = g; i < total4; i += stride) {
        float4 v; size_t dst; short* d;
        if (i < NXELEM/4) {
            v = ((const float4*)x)[i];
            dst = (size_t)i*4; d = xf;
        } else {
            int e = (i - NXELEM/4)*4;
            int R = e >> 9;                 // 0..1023: h*128 + (q:0-63 | k:64-127)
            int k = e & 511;
            int h = R >> 7;
            int p = R & 127;
            int m = p >> 6;                 // 0=q, 1=k
            int c = p & 63;
            const float* W = m ? Wk : Wq;
            v = *(const float4*)&W[(size_t)(h*HD + c)*DM + k];
            dst = (size_t)R*DM + k; d = wf;
        }
        short4 hv;
        hv.x = cvt1(v.x); hv.y = cvt1(v.y); hv.z = cvt1(v.z); hv.w = cvt1(v.w);
        *(short4*)&d[dst] = hv;
    }
    // background fill: rows < ROW0 of out are just bo
    {
        const float4* b4 = (const float4*)bo;
        float4* o4 = (float4*)out;
        const int fill4 = ROW0*DM/4;
        for (int i = g; i < fill4; i += stride) o4[i] = b4[i & 127];
    }
    if (g < NWROW) {
        int h = g >> 7, p = g & 127, m = p >> 6, c = p & 63;
        bcat[g] = (m ? bk : bq)[h*HD + c];
    }
    if (g < NH*RTOT) sig[g] = 0.f;      // 32768
    if (g < 16*DM)   sbar[g] = 0.f;     // 8192
    if (g < 16)      Ssum[g] = 0.f;
}

// ---- Kernel 1: fp16 MFMA q,k GEMM -> raw sigma scores (+qsel) -----------------
// grid (32 rowchunks, 8 heads, 2 j-halves): block = 128 rows x 32 j's (q&k).
// B (64 cols x 512 K fp16 = 64KB) staged in LDS ONCE (single barrier).
// Main loop: waves process row-tiles independently, A-frags straight from
// global, sigma j-partials combined across blocks via global atomicAdd.
// NO barriers, no cross-wave traffic in the main loop.
__global__ __launch_bounds__(256, 2) void qk_gemm(
    const _Float16* __restrict__ xf, const _Float16* __restrict__ wf,
    const float* __restrict__ bcat,
    float* __restrict__ sig, float* __restrict__ qsel)
{
    __shared__ __align__(16) char smem[65536];   // B: 64 chunks x 1KB (t*16+kc)

    const int tid  = threadIdx.x;
    const int w    = tid >> 6;
    const int lane = tid & 63;
    const int lrow = lane & 15;
    const int lk8  = lane >> 4;
    const int rc   = blockIdx.x;     // 0..31
    const int h    = blockIdx.y;     // 0..7
    const int jh   = blockIdx.z;     // 0..1
    const int r0   = rc * 128;

    // stage B: wave w stages chunks [w*16, w*16+16) -> tile t=w, kc=ci
    {
        const int t = w;
        const int bcol = (t < 2) ? (jh*32 + t*16) : (64 + jh*32 + (t-2)*16);
        const _Float16* src = wf + (size_t)(h*128 + bcol + lrow)*DM + lk8*8;
        for (int ci = 0; ci < 16; ++ci)
            gld16(src + ci*32, smem + (w*16 + ci)*1024);
    }
    __syncthreads();

    const float bq0 = bcat[h*128 + jh*32 + lrow];
    const float bq1 = bcat[h*128 + jh*32 + 16 + lrow];
    const float bk0 = bcat[h*128 + 64 + jh*32 + lrow];
    const float bk1 = bcat[h*128 + 64 + jh*32 + 16 + lrow];

    #pragma unroll
    for (int nn = 0; nn < 2; ++nn) {
        const int n = w + nn*4;              // row-tile 0..7
        const int rbase = r0 + n*16;

        half8 A[16];
        const _Float16* pa = xf + (size_t)(rbase + lrow)*DM + lk8*8;
        #pragma unroll
        for (int kc = 0; kc < 16; ++kc)
            A[kc] = *(const half8*)(pa + kc*32);

        floatx4 aq0 = (floatx4)0.f, aq1 = (floatx4)0.f;
        floatx4 ak0 = (floatx4)0.f, ak1 = (floatx4)0.f;
        #pragma unroll
        for (int kc = 0; kc < 16; ++kc) {
            half8 b0 = *(const half8*)(smem + ( 0 + kc)*1024 + lane*16);
            half8 b1 = *(const half8*)(smem + (16 + kc)*1024 + lane*16);
            half8 b2 = *(const half8*)(smem + (32 + kc)*1024 + lane*16);
            half8 b3 = *(const half8*)(smem + (48 + kc)*1024 + lane*16);
            aq0 = __builtin_amdgcn_mfma_f32_16x16x32_f16(A[kc], b0, aq0, 0, 0, 0);
            aq1 = __builtin_amdgcn_mfma_f32_16x16x32_f16(A[kc], b1, aq1, 0, 0, 0);
            ak0 = __builtin_amdgcn_mfma_f32_16x16x32_f16(A[kc], b2, ak0, 0, 0, 0);
            ak1 = __builtin_amdgcn_mfma_f32_16x16x32_f16(A[kc], b3, ak1, 0, 0, 0);
        }

        // epilogue: per row, sigma j-partial = sum_j (q+bq)(k+bk) over this
        // block's 32 j's; reduce over lrow lanes; atomic into sig.
        #pragma unroll
        for (int r = 0; r < 4; ++r) {
            float q0 = aq0[r] + bq0, q1 = aq1[r] + bq1;
            float k0 = ak0[r] + bk0, k1 = ak1[r] + bk1;
            float p = q0*k0 + q1*k1;
            p += __shfl_xor(p, 1, 64);
            p += __shfl_xor(p, 2, 64);
            p += __shfl_xor(p, 4, 64);
            p += __shfl_xor(p, 8, 64);
            int row = rbase + lk8*4 + r;
            if (lrow == 0) atomicAdd(&sig[h*RTOT + row], p);
            if (((row >> 1) & 63) == 63) {
                int b  = row & 1;
                int wi = row >> 7;           // (row>>1)>>6
                float* qd = &qsel[((size_t)(b*NH + h)*T_KEEP + wi)*64];
                qd[jh*32 + lrow]      = q0;
                qd[jh*32 + 16 + lrow] = q1;
            }
        }
    }
}

// ---- Kernel 2: sigma = sigmoid(raw*scale); sbar = sum sigma*x; Ssum -----------
// grid 64: block (b = bx&1, s-range 64). Coalesced x reads, 8 FMA/elem.
__global__ __launch_bounds__(256) void sbark(
    const float* __restrict__ x, const float* __restrict__ sigr,
    const float* __restrict__ beta, float* __restrict__ sbar,
    float* __restrict__ Ssum)
{
    __shared__ float ss[64][NH];
    const int tid = threadIdx.x;
    const int b = blockIdx.x & 1;
    const int s0 = (blockIdx.x >> 1) * 64;

    for (int i = tid; i < 64*NH; i += 256) {
        int s = i >> 3, hh = i & 7;
        float raw = sigr[hh*RTOT + (s0 + s)*2 + b];
        float isc = 1.0f / (8.0f * expf(beta[hh]));
        ss[s][hh] = 1.0f / (1.0f + expf(-raw * isc));
    }
    __syncthreads();
    if (tid < NH) {
        float t = 0.f;
        for (int s = 0; s < 64; ++s) t += ss[s][tid];
        atomicAdd(&Ssum[b*NH + tid], t);
    }
    #pragma unroll
    for (int cp = 0; cp < 2; ++cp) {
        int c = cp*256 + tid;
        float a8[NH];
        #pragma unroll
        for (int hh = 0; hh < NH; ++hh) a8[hh] = 0.f;
        for (int s = 0; s < 64; ++s) {
            float xv = x[(size_t)((s0 + s)*2 + b)*DM + c];
            #pragma unroll
            for (int hh = 0; hh < NH; ++hh) a8[hh] += ss[s][hh] * xv;
        }
        #pragma unroll
        for (int hh = 0; hh < NH; ++hh)
            atomicAdd(&sbar[(b*NH + hh)*DM + c], a8[hh]);
    }
}

// ---- Kernel 3: kbar/vbar = W*sbar + b*S; coef softmax; G row ------------------
// grid 16 (z = b*8+h), block 256.
__global__ __launch_bounds__(256) void headk(
    const float* __restrict__ qsel, const float* __restrict__ beta,
    const float* __restrict__ sbar, const float* __restrict__ Ssum,
    const float* __restrict__ Wk, const float* __restrict__ bk,
    const float* __restrict__ Wv, const float* __restrict__ bv,
    const float* __restrict__ Wo,
    float* __restrict__ coef, float* __restrict__ G)
{
    const int z = blockIdx.x;
    const int h = z & 7;
    const int tid = threadIdx.x;

    __shared__ float s_sb[DM];
    __shared__ float s_red[64][4];
    __shared__ float s_kb[64], s_vb[64];
    __shared__ float s_part[T_KEEP][8];
    __shared__ float s_gp[64][4];

    s_sb[tid]       = sbar[z*DM + tid];
    s_sb[tid + 256] = sbar[z*DM + 256 + tid];
    __syncthreads();
    const float S = Ssum[z];

    // kbar = Wk_h * sbar + bk*S  (4 threads per output j)
    {
        int j = tid >> 2, kp = tid & 3;
        const float* wr = &Wk[(size_t)(h*HD + j)*DM + kp*128];
        float a = 0.f;
        #pragma unroll
        for (int k = 0; k < 128; k += 4) {
            float4 w4 = *(const float4*)&wr[k];
            int k0 = kp*128 + k;
            a += w4.x*s_sb[k0] + w4.y*s_sb[k0+1] + w4.z*s_sb[k0+2] + w4.w*s_sb[k0+3];
        }
        s_red[j][kp] = a;
    }
    __syncthreads();
    if (tid < 64) s_kb[tid] = s_red[tid][0]+s_red[tid][1]+s_red[tid][2]+s_red[tid][3]
                              + bk[h*HD + tid]*S;
    __syncthreads();
    // vbar = Wv_h * sbar + bv*S
    {
        int j = tid >> 2, kp = tid & 3;
        const float* wr = &Wv[(size_t)(h*HD + j)*DM + kp*128];
        float a = 0.f;
        #pragma unroll
        for (int k = 0; k < 128; k += 4) {
            float4 w4 = *(const float4*)&wr[k];
            int k0 = kp*128 + k;
            a += w4.x*s_sb[k0] + w4.y*s_sb[k0+1] + w4.z*s_sb[k0+2] + w4.w*s_sb[k0+3];
        }
        s_red[j][kp] = a;
    }
    __syncthreads();
    if (tid < 64) s_vb[tid] = s_red[tid][0]+s_red[tid][1]+s_red[tid][2]+s_red[tid][3]
                              + bv[h*HD + tid]*S;
    __syncthreads();

    // coef: scores via thread-parallel partials, softmax with sink
    {
        int wi = tid >> 3, jg = tid & 7;
        const float* qrow = &qsel[((size_t)z*T_KEEP + wi)*64 + jg*8];
        float4 q1 = *(const float4*)qrow;
        float4 q2 = *(const float4*)(qrow + 4);
        int j0 = jg*8;
        float p = q1.x*s_kb[j0] + q1.y*s_kb[j0+1] + q1.z*s_kb[j0+2] + q1.w*s_kb[j0+3]
                + q2.x*s_kb[j0+4] + q2.y*s_kb[j0+5] + q2.z*s_kb[j0+6] + q2.w*s_kb[j0+7];
        s_part[wi][jg] = p;
    }
    __syncthreads();
    if (tid < T_KEEP) {
        float sc = 0.f;
        #pragma unroll
        for (int gg = 0; gg < 8; ++gg) sc += s_part[tid][gg];
        sc *= 1.0f / (8.0f * expf(beta[h]));
        float m = sc;
        #pragma unroll
        for (int off = 16; off > 0; off >>= 1) m = fmaxf(m, __shfl_xor(m, off, 64));
        m = fmaxf(m, 0.f);                       // sink logit = 0
        float e = expf(sc - m);
        float d = e;
        #pragma unroll
        for (int off = 16; off > 0; off >>= 1) d += __shfl_xor(d, off, 64);
        d += expf(-m);                           // sink term
        float c = e / d;
        if (tid == T_KEEP-1) c += 1.0f;          // iter-0 contribution
        coef[z*T_KEEP + tid] = c;
    }

    // G: 8 passes; 4 threads per column, 16 j each; LDS reduce
    const int cq = tid >> 2;
    const int jg = tid & 3;
    #pragma unroll
    for (int it = 0; it < 8; ++it) {
        int c = it*64 + cq;
        const float* wrow = &Wo[(size_t)c*DM + h*HD + jg*16];
        float a = 0.f;
        #pragma unroll
        for (int jj = 0; jj < 16; jj += 4) {
            float4 wv = *(const float4*)&wrow[jj];
            int j0 = jg*16 + jj;
            a += wv.x*s_vb[j0] + wv.y*s_vb[j0+1] + wv.z*s_vb[j0+2] + wv.w*s_vb[j0+3];
        }
        s_gp[cq][jg] = a;
        __syncthreads();
        if (tid < 64)
            G[(size_t)z*DM + it*64 + tid] = s_gp[tid][0] + s_gp[tid][1] + s_gp[tid][2] + s_gp[tid][3];
        __syncthreads();
    }
}

// ---- Kernel 4: output rows from coef x G --------------------------------------
__global__ __launch_bounds__(256) void outk3(
    const float* __restrict__ coef, const float* __restrict__ G,
    const float* __restrict__ bo, float* __restrict__ out)
{
    const int a = blockIdx.x;
    const int b = a & 1;
    const int wi = a >> 1;
    const int tid = threadIdx.x;
    __shared__ float s_cf[NH];
    if (tid < NH) s_cf[tid] = coef[(b*NH + tid)*T_KEEP + wi];
    __syncthreads();
    for (int c = tid; c < DM; c += 256) {
        float v = bo[c];
        #pragma unroll
        for (int h = 0; h < NH; ++h)
            v += s_cf[h] * G[(size_t)(b*NH + h)*DM + c];
        out[(size_t)(ROW0 + a)*DM + c] = v;
    }
}

extern "C" void kernel_launch(void* const* d_in, const int* in_sizes, int n_in,
                              void* d_out, int out_size, void* d_ws, size_t ws_size,
                              hipStream_t stream) {
    const float* x    = (const float*)d_in[0];
    const float* Wq   = (const float*)d_in[1];
    const float* bq   = (const float*)d_in[2];
    const float* Wk   = (const float*)d_in[3];
    const float* bk   = (const float*)d_in[4];
    const float* Wv   = (const float*)d_in[5];
    const float* bv   = (const float*)d_in[6];
    const float* Wo   = (const float*)d_in[7];
    const float* bo   = (const float*)d_in[8];
    const float* beta = (const float*)d_in[9];

    char* ws = (char*)d_ws;
    float* sig  = (float*)(ws + 0);         // 128 KB [h][4096] raw scores
    float* qsel = (float*)(ws + 131072);    // 128 KB
    float* sbar = (float*)(ws + 262144);    //  32 KB [z][512]
    float* Ssum = (float*)(ws + 294912);    //  64 B  [z]
    float* bcat = (float*)(ws + 295168);    //   4 KB [h][128] (q|k)
    float* coef = (float*)(ws + 299264);    //   2 KB
    float* G    = (float*)(ws + 301312);    //  32 KB
    short* xf   = (short*)(ws + 335872);    //   4 MB
    short* wf   = (short*)(ws + 335872 + 4194304);   // 1 MB [h][128][512]
    float* out  = (float*)d_out;

    convert<<<2048, 256, 0, stream>>>(x, Wq, Wk, bq, bk, bo,
                                      xf, wf, bcat, sig, sbar, Ssum, out);
    dim3 g1(32, NH, 2);
    qk_gemm<<<g1, 256, 0, stream>>>((const _Float16*)xf, (const _Float16*)wf,
                                    bcat, sig, qsel);
    sbark<<<64, 256, 0, stream>>>(x, sig, beta, sbar, Ssum);
    headk<<<16, 256, 0, stream>>>(qsel, beta, sbar, Ssum, Wk, bk, Wv, bv, Wo, coef, G);
    outk3<<<64, 256, 0, stream>>>(coef, G, bo, out);
}